// Round 17
// baseline (309.969 us; speedup 1.0000x reference)
//
#include <hip/hip_runtime.h>
#include <hip/hip_bf16.h>
#include <math.h>

typedef unsigned short u16;
typedef __attribute__((ext_vector_type(8))) short bf16x8;
typedef __attribute__((ext_vector_type(4))) float f32x4;
typedef __attribute__((ext_vector_type(4))) u16 u16x4;
typedef __attribute__((ext_vector_type(8))) u16 u16x8;

#define S_LEN   1536
#define HID     2880
#define NH      64
#define NKV     8
#define DH      64
#define QKV_N   5120   // 64*64 + 2*8*64
#define QDIM    4096   // 64*64
#define KVDIM   512    // 8*64
#define SMSCALE 0.125f
#define LOG2E   1.44269504f
#define EPSV    1e-5f

__device__ __forceinline__ float b2f(u16 u) {
    unsigned int v = ((unsigned int)u) << 16;
    float f; __builtin_memcpy(&f, &v, 4); return f;
}
__device__ __forceinline__ u16 f2b(float f) {
    __hip_bfloat16 h = __float2bfloat16(f);
    return *reinterpret_cast<u16*>(&h);
}
// bare v_exp_f32 (2^x). NOT libm exp2f: with IEEE-denormal default, OCML's
// exp2f takes a denormal-fixup path (~8 extra VALU/call) -- r11's regression.
__device__ __forceinline__ float exp2n(float x) { return __builtin_amdgcn_exp2f(x); }
__device__ __forceinline__ void gld16(const u16* g, u16* l) {
    __builtin_amdgcn_global_load_lds(
        (const __attribute__((address_space(1))) unsigned int*)g,
        (__attribute__((address_space(3))) unsigned int*)l, 16, 0, 0);
}
// s_waitcnt immediates (gfx9 encoding: vm[3:0],[15:14]; exp[6:4]; lgkm[11:8])
#define WAIT_VM6()   __builtin_amdgcn_s_waitcnt(0xF76)  // vmcnt<=6, lgkm/exp free
#define WAIT_VM0()   __builtin_amdgcn_s_waitcnt(0xF70)  // vmcnt<=0
#define WAIT_LGKM0() __builtin_amdgcn_s_waitcnt(0xC07F) // lgkmcnt<=0, vm/exp free

// ---------------- 0. prep: rmsnorm + rope tables ONLY ----------------
// r17: weight fp32->bf16 conversion FUSED INTO GEMM B-staging (the GEMMs are
// schedule-bound with idle memory+VALU; a standalone conversion pass measured
// ~50us at a 2.5 TB/s mixed-traffic ceiling across 3 probes). prep is now
// tiny: [0,1536) rmsnorm; [1536,1728) rope tables.
__global__ __launch_bounds__(256) void prep_kernel(
    const float* __restrict__ x, const float* __restrict__ ns, u16* __restrict__ t,
    float* __restrict__ cosT, float* __restrict__ sinT)
{
    __shared__ float red[4];
    const int b = blockIdx.x;
    const int tid = threadIdx.x;
    if (b < 1536) {                        // rmsnorm row s (float4 loads)
        const int s = b;
        const float4* xr4 = (const float4*)(x + (size_t)s * HID);   // 720 float4s
        float ss = 0.f;
        for (int i = tid; i < 720; i += 256) {
            float4 v = xr4[i];
            ss += v.x * v.x + v.y * v.y + v.z * v.z + v.w * v.w;
        }
        for (int off = 32; off > 0; off >>= 1) ss += __shfl_down(ss, off);
        if ((tid & 63) == 0) red[tid >> 6] = ss;
        __syncthreads();
        float tot = red[0] + red[1] + red[2] + red[3];
        float scale = rsqrtf(tot / (float)HID + EPSV);
        const float4* ns4 = (const float4*)ns;
        u16x4* tr4 = (u16x4*)(t + (size_t)s * HID);
        for (int i = tid; i < 720; i += 256) {
            float4 v = xr4[i];
            float4 nv = ns4[i];
            u16x4 o;
            o.x = f2b(v.x * scale * nv.x);
            o.y = f2b(v.y * scale * nv.y);
            o.z = f2b(v.z * scale * nv.z);
            o.w = f2b(v.w * scale * nv.w);
            tr4[i] = o;
        }
    } else {                               // YaRN rope tables (fp64 to match ref)
        int idx = (b - 1536) * 256 + tid;
        if (idx >= S_LEN * 32) return;
        int s = idx >> 5, i = idx & 31;
        const double PI2 = 6.283185307179586476925286766559;
        double base = 150000.0;
        double freq = pow(base, (double)(2 * i) / 64.0);
        double conc = 0.1 * log(32.0) + 1.0;
        double low  = 32.0 * log(4096.0 / (32.0 * PI2)) / log(base);
        double high = 32.0 * log(4096.0 / (1.0  * PI2)) / log(base);
        double interp = 1.0 / (32.0 * freq);
        double extrap = 1.0 / freq;
        double ramp = ((double)i - low) / (high - low);
        double msk = 1.0 - fmin(fmax(ramp, 0.0), 1.0);
        double invf = interp * (1.0 - msk) + extrap * msk;
        double ang = (double)s * invf;
        cosT[idx] = (float)(cos(ang) * conc);
        sinT[idx] = (float)(sin(ang) * conc);
    }
}

// ---------------- 3. split-K GEMM, 256x256, BK=64, fp32-B convert-on-stage ----------------
// Cp[z][M,N](bf16) = A[M,K](bf16) * B[N,K]^T(FP32, converted during staging).
// r17: B-staging = attn-proven issue-early/write-late. bissue loads 4xfloat4
// (fp32 weights) where stB's gld_lds used to run; cvt + 2x ds_write_b128 one
// K-tile later, just before the barrier that publishes the buffer. Layout in
// LDS is IDENTICAL to what gld_lds produced (row-major [256][32], thread tid
// -> elems tid*8 / 4096+tid*8). Safety inherited from the r2 core (x8
// verified): writes to a buffer land >=2 barriers after its last reads (WAR);
// lgkmcnt(0) before each barrier publishes ds_writes (RAW); WAIT_VM6 at both
// barriers guarantees A-tile gld_lds drain by vmcnt FIFO order (needed ops
// are >=8 vmem-ops older than the 6 allowed in flight). A stays gld_lds.
// Numerics: same f2b rounding as the old conversion pass -> bit-identical.
// z: 0,1 -> Cp + z*M*N (contiguous); 2 -> Cp2; 3 -> Cp3.
__global__ __launch_bounds__(512, 2) void gemm_bt_8p_kernel(
    const u16* __restrict__ A, const float* __restrict__ B,
    u16* __restrict__ Cp, u16* __restrict__ Cp2, u16* __restrict__ Cp3,
    int M, int N, int K, int it0, int it1, int ntm, int ntn)
{
    extern __shared__ __align__(16) u16 smem[];
    u16* sAp = smem;            // [2][2][256*32] = 32768 elems
    u16* sBp = smem + 32768;

    const int tid  = threadIdx.x;
    const int wave = tid >> 6, lane = tid & 63;
    const int quad = lane >> 4, l16 = lane & 15;
    const int wm = wave >> 2, wn = wave & 3;

    // XCD-aware swizzle, general bijective form (m204)
    const int nwg  = gridDim.x;
    const int q8   = nwg >> 3, r8 = nwg & 7;
    const int flat = blockIdx.x;
    const int xcd  = flat & 7, loc = flat >> 3;
    const int swz  = (xcd < r8) ? xcd * (q8 + 1) + loc
                                : r8 * (q8 + 1) + (xcd - r8) * q8 + loc;
    const int tpz  = ntm * ntn;
    const int z    = swz / tpz;
    const int rem  = swz - z * tpz;
    const int nt   = rem / ntm;
    const int mt   = rem - nt * ntm;
    const int bm = mt * 256, bn = nt * 256;
    const int niter = z ? it1 : it0;
    const int kb    = z ? (it0 + (z - 1) * it1) * 64 : 0;
    u16* C = (z == 0) ? Cp : (z == 1) ? (Cp + (size_t)M * N) : (z == 2) ? Cp2 : Cp3;

    // staging addresses: thread covers row (tid>>2) [+128], k-elems (tid&3)*8
    const int r2  = tid >> 2;
    const int ks8 = (tid & 3) * 8;
    const u16* gA0 = A + (size_t)(bm + r2) * K + kb + ks8;
    const u16* gA1 = gA0 + (size_t)128 * K;
    int brA = bn + r2;       if (brA > N - 1) brA = N - 1;   // N-pad clamp
    int brB = bn + 128 + r2; if (brB > N - 1) brB = N - 1;
    const float* gB0 = B + (size_t)brA * K + kb + ks8;       // fp32 weights
    const float* gB1 = B + (size_t)brB * K + kb + ks8;
    const int sw = wave * 512;          // wave-uniform LDS stage base (elems)

    f32x4 acc[8][4];
    #pragma unroll
    for (int i = 0; i < 8; i++)
        #pragma unroll
        for (int j = 0; j < 4; j++) acc[i][j] = (f32x4){0.f, 0.f, 0.f, 0.f};

    auto stA = [&](int c, int kh, int t) {
        u16* d = sAp + (((c << 1) | kh) << 13);
        const int koff = t * 64 + kh * 32;
        gld16(gA0 + koff, d + sw);
        gld16(gA1 + koff, d + 4096 + sw);
    };

    // B fp32 staging registers: one set per k-half, in flight one K-tile deep
    float4 p0a, p0b, p0c, p0d;          // kh=0
    float4 p1a, p1b, p1c, p1d;          // kh=1
    auto bissue0 = [&](int t) {
        const float* q0 = gB0 + t * 64;
        const float* q1 = gB1 + t * 64;
        p0a = *(const float4*)q0; p0b = *(const float4*)(q0 + 4);
        p0c = *(const float4*)q1; p0d = *(const float4*)(q1 + 4);
    };
    auto bissue1 = [&](int t) {
        const float* q0 = gB0 + t * 64 + 32;
        const float* q1 = gB1 + t * 64 + 32;
        p1a = *(const float4*)q0; p1b = *(const float4*)(q0 + 4);
        p1c = *(const float4*)q1; p1d = *(const float4*)(q1 + 4);
    };
    auto bwr = [&](int c, int kh, float4 va, float4 vb, float4 vc, float4 vd) {
        u16* d = sBp + (((c << 1) | kh) << 13) + tid * 8;
        bf16x8 o0, o1;
        o0[0] = f2b(va.x); o0[1] = f2b(va.y); o0[2] = f2b(va.z); o0[3] = f2b(va.w);
        o0[4] = f2b(vb.x); o0[5] = f2b(vb.y); o0[6] = f2b(vb.z); o0[7] = f2b(vb.w);
        o1[0] = f2b(vc.x); o1[1] = f2b(vc.y); o1[2] = f2b(vc.z); o1[3] = f2b(vc.w);
        o1[4] = f2b(vd.x); o1[5] = f2b(vd.y); o1[6] = f2b(vd.z); o1[7] = f2b(vd.w);
        *(bf16x8*)d = o0;               // row brA chunk (region [0,4096))
        *(bf16x8*)(d + 4096) = o1;      // row brB chunk (region [4096,8192))
    };

    bf16x8 bv[4];
    const int arow = wm * 128 + l16;
    const int brow = wn * 64 + l16;
    auto rdB = [&](int c, int ks) {
        const u16* p = sBp + (((c << 1) | ks) << 13) + brow * 32 + quad * 8;
        #pragma unroll
        for (int nf = 0; nf < 4; nf++) bv[nf] = *(const bf16x8*)(p + nf * 16 * 32);
    };
    auto mmph = [&](int c, int ks, int mh) {
        const u16* p = sAp + (((c << 1) | ks) << 13) + (arow + mh * 64) * 32 + quad * 8;
        bf16x8 av[4];
        #pragma unroll
        for (int mf = 0; mf < 4; mf++) av[mf] = *(const bf16x8*)(p + mf * 16 * 32);
        __builtin_amdgcn_s_setprio(1);
        #pragma unroll
        for (int mf = 0; mf < 4; mf++)
            #pragma unroll
            for (int nf = 0; nf < 4; nf++)
                acc[mh * 4 + mf][nf] = __builtin_amdgcn_mfma_f32_16x16x32_bf16(
                    av[mf], bv[nf], acc[mh * 4 + mf][nf], 0, 0, 0);
        __builtin_amdgcn_s_setprio(0);
    };

    // prologue: A tile 0 (gld_lds) + B tile 0 fp32 loads (A first: FIFO order)
    stA(0, 0, 0); stA(0, 1, 0);
    bissue0(0); bissue1(0);

    for (int t = 0; t < niter - 1; ++t) {
        const int c = t & 1;
        // phase 0 (k0): publish tile t k0; prefetch tile t+1
        stA(c ^ 1, 0, t + 1);
        bwr(c, 0, p0a, p0b, p0c, p0d);    // cvt waits breg k0(t) -> drains A(t,k0) (FIFO)
        WAIT_VM6();                        // belt+braces: <=6 newest in flight
        WAIT_LGKM0();                      // ds_writes visible
        __builtin_amdgcn_s_barrier();
        bissue0(t + 1);                    // reload breg k0 for tile t+1
        rdB(c, 0); mmph(c, 0, 0);
        // phase 1
        mmph(c, 0, 1);
        // phase 2 (k1)
        stA(c ^ 1, 1, t + 1);
        bwr(c, 1, p1a, p1b, p1c, p1d);
        WAIT_VM6();
        WAIT_LGKM0();
        __builtin_amdgcn_s_barrier();
        bissue1(t + 1);
        rdB(c, 1); mmph(c, 1, 0);
        // phase 3
        mmph(c, 1, 1);
    }
    {   // last tile: nothing staged for t+1 (drain to 0)
        const int c = (niter - 1) & 1;
        bwr(c, 0, p0a, p0b, p0c, p0d);
        WAIT_VM0();
        WAIT_LGKM0();
        __builtin_amdgcn_s_barrier();
        rdB(c, 0); mmph(c, 0, 0); mmph(c, 0, 1);
        bwr(c, 1, p1a, p1b, p1c, p1d);
        WAIT_LGKM0();
        __builtin_amdgcn_s_barrier();
        rdB(c, 1); mmph(c, 1, 0); mmph(c, 1, 1);
    }

    #pragma unroll
    for (int im = 0; im < 8; im++) {
        const int row0 = bm + wm * 128 + im * 16 + quad * 4;
        #pragma unroll
        for (int nf = 0; nf < 4; nf++) {
            const int col = bn + wn * 64 + nf * 16 + l16;
            if (col < N) {
                #pragma unroll
                for (int r = 0; r < 4; r++)
                    C[(size_t)(row0 + r) * N + col] = f2b(acc[im][nf][r]);
            }
        }
    }
}

// ---------------- 4. RoPE apply (VECTORIZED) + split-K reduce + bias + FUSED V-transpose ----------------
// Grid sections: [0,1728) rope heads; [1728,1920) V-transpose blocks.
// Q is pre-scaled by SMSCALE*LOG2E: attention softmax uses native exp2.
__global__ __launch_bounds__(256) void rope_apply_kernel(
    const u16* __restrict__ p0, const u16* __restrict__ p1, const float* __restrict__ bias,
    const float* __restrict__ cosT, const float* __restrict__ sinT,
    u16* __restrict__ q_r, u16* __restrict__ k_r, u16* __restrict__ vt)
{
    __shared__ u16 tile[64][72];
    const int b = blockIdx.x;
    const int tid = threadIdx.x;
    if (b < 1728) {                      // rope heads: 64 Q + 8 K
        int idx = b * 256 + tid;         // s*288 + c, c in [0,288)
        int s = idx / 288;
        int c = idx - s * 288;
        const u16* r0p = p0 + (size_t)s * QKV_N;
        const u16* r1p = p1 + (size_t)s * QKV_N;
        int hh = c >> 2, j0 = (c & 3) * 8;
        int off = hh * 64;               // K heads land at QDIM+kh*64 = hh*64
        u16x8 a1 = *(const u16x8*)(r0p + off + j0);
        u16x8 b1 = *(const u16x8*)(r1p + off + j0);
        u16x8 a2 = *(const u16x8*)(r0p + off + 32 + j0);
        u16x8 b2 = *(const u16x8*)(r1p + off + 32 + j0);
        float bl[8], bh[8], cc[8], sn[8];
        *(float4*)&bl[0] = *(const float4*)(bias + off + j0);
        *(float4*)&bl[4] = *(const float4*)(bias + off + j0 + 4);
        *(float4*)&bh[0] = *(const float4*)(bias + off + 32 + j0);
        *(float4*)&bh[4] = *(const float4*)(bias + off + 32 + j0 + 4);
        *(float4*)&cc[0] = *(const float4*)(cosT + s * 32 + j0);
        *(float4*)&cc[4] = *(const float4*)(cosT + s * 32 + j0 + 4);
        *(float4*)&sn[0] = *(const float4*)(sinT + s * 32 + j0);
        *(float4*)&sn[4] = *(const float4*)(sinT + s * 32 + j0 + 4);
        const float scale = (hh < 64) ? SMSCALE * LOG2E : 1.0f;
        u16x8 lo, hi;
        #pragma unroll
        for (int j = 0; j < 8; j++) {
            float x1 = b2f(a1[j]) + b2f(b1[j]) + bl[j];
            float x2 = b2f(a2[j]) + b2f(b2[j]) + bh[j];
            lo[j] = f2b((x1 * cc[j] - x2 * sn[j]) * scale);
            hi[j] = f2b((x2 * cc[j] + x1 * sn[j]) * scale);
        }
        if (hh < 64) {
            u16* dst = q_r + (size_t)s * QDIM + off;
            *(u16x8*)(dst + j0) = lo;
            *(u16x8*)(dst + 32 + j0) = hi;
        } else {
            u16* dst = k_r + (size_t)s * KVDIM + (hh - 64) * 64;
            *(u16x8*)(dst + j0) = lo;
            *(u16x8*)(dst + 32 + j0) = hi;
        }
    } else {                             // V-transpose: vb in [0,192) = kvh*24 + sblk
        int vb = b - 1728;
        int kvh = vb / 24, sblk = vb - kvh * 24;
        int s0 = sblk * 64;
        int r = tid >> 3;                // 0..31
        int cc = (tid & 7) * 8;          // 0..56
        int off = QDIM + KVDIM + kvh * 64 + cc;
        float bb[8];
        *(float4*)&bb[0] = *(const float4*)(bias + off);
        *(float4*)&bb[4] = *(const float4*)(bias + off + 4);
        #pragma unroll
        for (int rr = 0; rr < 64; rr += 32) {
            int s = s0 + r + rr;
            u16x8 a = *(const u16x8*)(p0 + (size_t)s * QKV_N + off);
            u16x8 b2 = *(const u16x8*)(p1 + (size_t)s * QKV_N + off);
            #pragma unroll
            for (int j = 0; j < 8; j++)
                tile[cc + j][r + rr] = f2b(b2f(a[j]) + b2f(b2[j]) + bb[j]);
        }
        __syncthreads();
        #pragma unroll
        for (int rr = 0; rr < 64; rr += 32) {
            uint4 ov;
            u16* p = (u16*)&ov;
            #pragma unroll
            for (int j = 0; j < 8; j++) p[j] = tile[r + rr][cc + j];
            *(uint4*)(vt + (size_t)(kvh * 64 + r + rr) * S_LEN + s0 + cc) = ov;
        }
    }
}

// ---------------- 5. Flash attention, TRANSPOSED-SCORE form, native-exp2 softmax ----------------
// (round-2 structure + r12 exp2n + r14 ones-MFMA denominator & max3-tree.)
__global__ __launch_bounds__(256) void attn_kernel(
    const u16* __restrict__ q_r, const u16* __restrict__ k_r, const u16* __restrict__ vt,
    const float* __restrict__ sinks, u16* __restrict__ o)
{
    __shared__ __align__(16) u16 sK[2][64 * 72];   // keys x d, pad 72, double-buffered
    __shared__ __align__(16) u16 sVt[2][64 * 72];  // d x keys, pad 72, double-buffered
    __shared__ __align__(16) u16 sP[4 * 16 * 72];  // per-wave: 16 queries x 64 keys

    const int bx = blockIdx.x, h = blockIdx.y;
    const int kvh = h & 7;
    const int tid = threadIdx.x, wave = tid >> 6, lane = tid & 63;
    const int quad = lane >> 4, l16 = lane & 15;
    const int srow = tid >> 3;            // 0..31
    const int scol = (tid & 7) * 8;       // 0..56
    u16* sPw = sP + wave * 16 * 72;
    const float sinkv = sinks[h] * LOG2E;   // log2-domain

    bf16x8 vone;                          // bf16 1.0 in every slot (ones-MFMA A-frag)
    #pragma unroll
    for (int j = 0; j < 8; j++) vone[j] = (short)0x3F80;

    // async-stage registers (tile t+1 in flight while computing tile t)
    uint4 kreg0, kreg1, vreg0, vreg1;
    const u16* kbase = k_r + (size_t)srow * KVDIM + kvh * 64 + scol;
    const u16* vbase = vt + (size_t)(kvh * 64 + srow) * S_LEN + scol;

    auto issue = [&](int j0) {
        kreg0 = *(const uint4*)(kbase + (size_t)j0 * KVDIM);
        kreg1 = *(const uint4*)(kbase + (size_t)(j0 + 32) * KVDIM);
        vreg0 = *(const uint4*)(vbase + j0);
        vreg1 = *(const uint4*)(vbase + (size_t)32 * S_LEN + j0);
    };
    auto lwrite = [&](int c) {
        *(uint4*)(&sK[c][srow * 72 + scol])        = kreg0;
        *(uint4*)(&sK[c][(srow + 32) * 72 + scol]) = kreg1;
        *(uint4*)(&sVt[c][srow * 72 + scol])        = vreg0;
        *(uint4*)(&sVt[c][(srow + 32) * 72 + scol]) = vreg1;
    };

    for (int phase = 0; phase < 2; ++phase) {
        const int qt = phase ? (23 - bx) : bx;
        const int q_i = qt * 64 + wave * 16 + l16;      // this lane's query row
        const u16* qp = q_r + (size_t)q_i * QDIM + h * 64 + quad * 8;
        bf16x8 aq0 = *(const bf16x8*)(qp);
        bf16x8 aq1 = *(const bf16x8*)(qp + 32);

        float m_i = sinkv, l_i = 1.0f;
        f32x4 acc[4];
        #pragma unroll
        for (int dt = 0; dt < 4; dt++) acc[dt] = (f32x4){0.f, 0.f, 0.f, 0.f};

        const int ntile = qt + 1;
        issue(0);
        __syncthreads();     // phase boundary: all waves done reading prev phase's LDS

        for (int tt = 0; tt < ntile; ++tt) {
            const int c = tt & 1;
            lwrite(c);                           // reg->LDS (implicit vmcnt wait, hidden)
            if (tt + 1 < ntile) issue((tt + 1) * 64);   // prefetch next tile
            WAIT_LGKM0();                        // my ds_writes visible
            __builtin_amdgcn_s_barrier();        // everyone's tile tt staged; buf c^1 free

            // S^T: 64 keys (m, 4 tiles) x 16 queries (n) per wave
            f32x4 sc[4];
            __builtin_amdgcn_s_setprio(1);
            #pragma unroll
            for (int nt = 0; nt < 4; nt++) {
                const u16* kp = &sK[c][(nt * 16 + l16) * 72 + quad * 8];
                bf16x8 bk0 = *(const bf16x8*)(kp);
                bf16x8 bk1 = *(const bf16x8*)(kp + 32);
                f32x4 s0 = (f32x4){0.f, 0.f, 0.f, 0.f};
                s0 = __builtin_amdgcn_mfma_f32_16x16x32_bf16(bk0, aq0, s0, 0, 0, 0);  // swapped!
                s0 = __builtin_amdgcn_mfma_f32_16x16x32_bf16(bk1, aq1, s0, 0, 0, 0);
                sc[nt] = s0;
            }
            __builtin_amdgcn_s_setprio(0);

            // causal mask: only the diagonal chunk (block-uniform branch)
            if (tt == qt) {
                #pragma unroll
                for (int nt = 0; nt < 4; nt++)
                    #pragma unroll
                    for (int r = 0; r < 4; r++)
                        if (tt * 64 + nt * 16 + quad * 4 + r > q_i) sc[nt][r] = -INFINITY;
            }

            // per-lane online softmax (log2 domain, native exp2), defer-max THR=11
            float a0 = fmaxf(fmaxf(sc[0][0], sc[0][1]), sc[0][2]);
            float a1 = fmaxf(fmaxf(sc[0][3], sc[1][0]), sc[1][1]);
            float a2 = fmaxf(fmaxf(sc[1][2], sc[1][3]), sc[2][0]);
            float a3 = fmaxf(fmaxf(sc[2][1], sc[2][2]), sc[2][3]);
            float a4 = fmaxf(fmaxf(sc[3][0], sc[3][1]), sc[3][2]);
            float vmax = fmaxf(fmaxf(fmaxf(a0, a1), fmaxf(a2, a3)),
                               fmaxf(a4, sc[3][3]));
            vmax = fmaxf(vmax, __shfl_xor(vmax, 16));
            vmax = fmaxf(vmax, __shfl_xor(vmax, 32));
            if (__any(vmax > m_i + 11.0f)) {     // rescale only when max grew enough
                float mnew = fmaxf(m_i, vmax);
                float alpha = exp2n(m_i - mnew);
                l_i *= alpha;
                #pragma unroll
                for (int dt = 0; dt < 4; dt++)
                    #pragma unroll
                    for (int r = 0; r < 4; r++) acc[dt][r] *= alpha;
                m_i = mnew;
            }
            u16x4 pk[4];
            #pragma unroll
            for (int nt = 0; nt < 4; nt++) {
                #pragma unroll
                for (int r = 0; r < 4; r++)
                    pk[nt][r] = f2b(exp2n(sc[nt][r] - m_i));   // bounded by 2^11
            }
            // P[q][key]: 4 contiguous keys per (nt,quad) -> packed 8B stores
            #pragma unroll
            for (int nt = 0; nt < 4; nt++)
                *(u16x4*)(sPw + l16 * 72 + nt * 16 + quad * 4) = pk[nt];
            __threadfence_block();   // order sP writes before cross-lane reads (wave-internal)

            // O^T += V^T (64xd as A) * P (16q x 64k as B); denominator via
            // ones-MFMA: every row of mfma(ones, P) = sum_k P[k][q].
            bf16x8 ap0 = *(const bf16x8*)(sPw + l16 * 72 + quad * 8);
            bf16x8 ap1 = *(const bf16x8*)(sPw + l16 * 72 + 32 + quad * 8);
            __builtin_amdgcn_s_setprio(1);
            f32x4 lsum = (f32x4){0.f, 0.f, 0.f, 0.f};
            lsum = __builtin_amdgcn_mfma_f32_16x16x32_bf16(vone, ap0, lsum, 0, 0, 0);
            lsum = __builtin_amdgcn_mfma_f32_16x16x32_bf16(vone, ap1, lsum, 0, 0, 0);
            #pragma unroll
            for (int dt = 0; dt < 4; dt++) {
                const u16* vp = &sVt[c][(dt * 16 + l16) * 72 + quad * 8];
                bf16x8 bv0 = *(const bf16x8*)(vp);
                bf16x8 bv1 = *(const bf16x8*)(vp + 32);
                acc[dt] = __builtin_amdgcn_mfma_f32_16x16x32_bf16(bv0, ap0, acc[dt], 0, 0, 0);  // swapped!
                acc[dt] = __builtin_amdgcn_mfma_f32_16x16x32_bf16(bv1, ap1, acc[dt], 0, 0, 0);
            }
            __builtin_amdgcn_s_setprio(0);
            l_i += lsum[0];                      // this lane's query denominator
        }

        // O^T: col=query(l16) = this lane's q_i; row = d = dt*16 + quad*4 + r
        float inv = 1.0f / l_i;
        #pragma unroll
        for (int dt = 0; dt < 4; dt++) {
            u16x4 ov;
            #pragma unroll
            for (int r = 0; r < 4; r++) ov[r] = f2b(acc[dt][r] * inv);
            *(u16x4*)(o + (size_t)q_i * QDIM + h * 64 + dt * 16 + quad * 4) = ov;
        }
    }
}

// ---------------- 6. final: out = p0 + p1 + p2 + out_b + x (8 elems/thread) ----------------
__global__ __launch_bounds__(256) void final_add_kernel(
    const u16* __restrict__ p0, const u16* __restrict__ p1, const u16* __restrict__ p2,
    const float* __restrict__ bias, const float* __restrict__ x, float* __restrict__ out)
{
    int i = blockIdx.x * 256 + threadIdx.x;        // group of 8 elems (8 | HID)
    int base = i * 8;
    int col = base % HID;
    float4 xo0 = *(const float4*)(x + base);
    float4 xo1 = *(const float4*)(x + base + 4);
    float4 bi0 = *(const float4*)(bias + col);
    float4 bi1 = *(const float4*)(bias + col + 4);
    u16x8 a = ((const u16x8*)p0)[i];
    u16x8 b = ((const u16x8*)p1)[i];
    u16x8 c = ((const u16x8*)p2)[i];
    float s[8];
    #pragma unroll
    for (int j = 0; j < 8; j++) s[j] = b2f(a[j]) + b2f(b[j]) + b2f(c[j]);
    float4 r0, r1;
    r0.x = s[0] + bi0.x + xo0.x;
    r0.y = s[1] + bi0.y + xo0.y;
    r0.z = s[2] + bi0.z + xo0.z;
    r0.w = s[3] + bi0.w + xo0.w;
    r1.x = s[4] + bi1.x + xo1.x;
    r1.y = s[5] + bi1.y + xo1.y;
    r1.z = s[6] + bi1.z + xo1.z;
    r1.w = s[7] + bi1.w + xo1.w;
    *(float4*)(out + base) = r0;
    *(float4*)(out + base + 4) = r1;
}

// ---------------- launch ----------------
extern "C" void kernel_launch(void* const* d_in, const int* in_sizes, int n_in,
                              void* d_out, int out_size, void* d_ws, size_t ws_size,
                              hipStream_t stream)
{
    const float* x          = (const float*)d_in[0];
    const float* sinks      = (const float*)d_in[1];
    const float* norm_scale = (const float*)d_in[2];
    const float* qkv_w      = (const float*)d_in[3];
    const float* qkv_b      = (const float*)d_in[4];
    const float* out_w      = (const float*)d_in[5];
    const float* out_b      = (const float*)d_in[6];
    float* out = (float*)d_out;

    char* ws = (char*)d_ws;
    // Phase A: t @0, qkvp0 @38.34M, qkvp1 @54.07M (= qkvp0 + M*N, CONTIGUOUS);
    // (qkv_w_bf/out_w_bf eliminated -- GEMMs read fp32 weights directly.)
    u16* t        = (u16*)(ws);                  // 8,847,360
    u16* qkvp0    = (u16*)(ws + 38338560);       // 15,728,640 -> 54,067,200
    u16* qkvp1    = (u16*)(ws + 54067200);       // 15,728,640 -> 69,795,840
    float* cosT   = (float*)(ws + 69795840);     // 196,608
    float* sinT   = (float*)(ws + 69992448);     // 196,608 (total 70,189,056)
    // Phase B: k_r @0, vt @1.57M, q_r @3.15M, o @15.73M,
    //   outp0 @28.31M, outp1 @37.16M (contiguous), outp2 @3.15M (overlays dead q_r)
    u16* k_r      = (u16*)(ws);                  // 1,572,864
    u16* vt       = (u16*)(ws + 1572864);        // 1,572,864 -> 3,145,728
    u16* q_r      = (u16*)(ws + 3145728);        // 12,582,912 -> 15,728,640
    u16* o        = (u16*)(ws + 15728640);       // 12,582,912 -> 28,311,552
    u16* outp0    = (u16*)(ws + 28311552);       // 8,847,360 -> 37,158,912
    u16* outp1    = (u16*)(ws + 37158912);       // 8,847,360 -> 46,006,272
    u16* outp2    = (u16*)(ws + 3145728);        // 8,847,360 -> 11,993,088 (inside dead q_r)

    static bool lds_attr_set = false;
    if (!lds_attr_set) {
        hipFuncSetAttribute(reinterpret_cast<const void*>(gemm_bt_8p_kernel),
                            hipFuncAttributeMaxDynamicSharedMemorySize, 131072);
        lds_attr_set = true;
    }

    // prep: rmsnorm [1536] + rope tables [192] (weight conversion now in-GEMM)
    prep_kernel<<<1728, 256, 0, stream>>>(x, norm_scale, t, cosT, sinT);
    // QKV GEMM: M=1536 N=5120 K=2880, B = fp32 qkv_w (convert-on-stage).
    // 256^2 tiles: 6x20=120, split-K 2 (23/22 K-steps of 64) -> 240 blocks.
    gemm_bt_8p_kernel<<<240, 512, 131072, stream>>>(
        t, qkv_w, qkvp0, qkvp0, qkvp0, S_LEN, QKV_N, HID, 23, 22, 6, 20);
    // rope [1728 blocks] + fused V-transpose [192 blocks]
    rope_apply_kernel<<<1920, 256, 0, stream>>>(
        qkvp0, qkvp1, qkv_b, cosT, sinT, q_r, k_r, vt);
    attn_kernel<<<dim3(12, NH), 256, 0, stream>>>(q_r, k_r, vt, sinks, o);
    // out GEMM: M=1536 N=2880 K=4096, B = fp32 out_w. 256^2 tiles: 6x12
    // (N padded 2880->3072, B rows clamped, stores masked), split-K 3
    // (22/21/21) -> 216 blocks. z=0,1 -> outp0,outp1 (contiguous); z=2 -> outp2.
    gemm_bt_8p_kernel<<<216, 512, 131072, stream>>>(
        o, out_w, outp0, outp2, outp2, S_LEN, HID, QDIM, 22, 21, 6, 12);
    final_add_kernel<<<S_LEN * HID / 8 / 256, 256, 0, stream>>>(
        outp0, outp1, outp2, out_b, x, out);
}

// Round 18
// 302.027 us; speedup vs baseline: 1.0263x; 1.0263x over previous
//
#include <hip/hip_runtime.h>
#include <hip/hip_bf16.h>
#include <math.h>

typedef unsigned short u16;
typedef __attribute__((ext_vector_type(8))) short bf16x8;
typedef __attribute__((ext_vector_type(4))) float f32x4;
typedef __attribute__((ext_vector_type(4))) u16 u16x4;
typedef __attribute__((ext_vector_type(8))) u16 u16x8;

#define S_LEN   1536
#define HID     2880
#define NH      64
#define NKV     8
#define DH      64
#define QKV_N   5120   // 64*64 + 2*8*64
#define QDIM    4096   // 64*64
#define KVDIM   512    // 8*64
#define SMSCALE 0.125f
#define LOG2E   1.44269504f
#define EPSV    1e-5f

__device__ __forceinline__ float b2f(u16 u) {
    unsigned int v = ((unsigned int)u) << 16;
    float f; __builtin_memcpy(&f, &v, 4); return f;
}
__device__ __forceinline__ u16 f2b(float f) {
    __hip_bfloat16 h = __float2bfloat16(f);
    return *reinterpret_cast<u16*>(&h);
}
// bare v_exp_f32 (2^x). NOT libm exp2f: with IEEE-denormal default, OCML's
// exp2f takes a denormal-fixup path (~8 extra VALU/call) -- r11's regression.
__device__ __forceinline__ float exp2n(float x) { return __builtin_amdgcn_exp2f(x); }
__device__ __forceinline__ void gld16(const u16* g, u16* l) {
    __builtin_amdgcn_global_load_lds(
        (const __attribute__((address_space(1))) unsigned int*)g,
        (__attribute__((address_space(3))) unsigned int*)l, 16, 0, 0);
}
// s_waitcnt immediates (gfx9 encoding: vm[3:0],[15:14]; exp[6:4]; lgkm[11:8])
#define WAIT_VM6()   __builtin_amdgcn_s_waitcnt(0xF76)  // vmcnt<=6, lgkm/exp free
#define WAIT_VM4()   __builtin_amdgcn_s_waitcnt(0xF74)  // vmcnt<=4
#define WAIT_VM0()   __builtin_amdgcn_s_waitcnt(0xF70)  // vmcnt<=0
#define WAIT_LGKM0() __builtin_amdgcn_s_waitcnt(0xC07F) // lgkmcnt<=0, vm/exp free

// ---------------- 0. fused prep: conv(qkv_w) [+ conv(out_w)] + rmsnorm + rope tables ----------------
// r17 post-mortem: fusing the fp32->bf16 conversion INTO GEMM B-staging
// regressed GEMMs 51->75us (reg-staged load waits land on the barrier
// critical path; fp32 B doubles fetch). The standalone pass at ~50us /
// 2.5 TB/s is the verified floor (r13/r16 widening probes both null).
// Sections: [0,14400) conv qkv_w; [14400,15936) rmsnorm (float4-vectorized);
// [15936,16128) rope tables; [16128,27648) conv out_w (fused path only).
__global__ __launch_bounds__(256) void prep_kernel(
    const float* __restrict__ qkv_w, u16* __restrict__ qkv_w_bf,
    const float* __restrict__ x, const float* __restrict__ ns, u16* __restrict__ t,
    float* __restrict__ cosT, float* __restrict__ sinT,
    const float* __restrict__ out_w, u16* __restrict__ out_w_bf)
{
    __shared__ float red[4];
    const int b = blockIdx.x;
    const int tid = threadIdx.x;
    if (b < 14400) {                       // conv qkv_w: 5120*2880/4 float4s
        int i = b * 256 + tid;
        float4 v = ((const float4*)qkv_w)[i];
        u16x4 o;
        o.x = f2b(v.x); o.y = f2b(v.y); o.z = f2b(v.z); o.w = f2b(v.w);
        ((u16x4*)qkv_w_bf)[i] = o;
    } else if (b < 15936) {                // rmsnorm row s (float4 loads)
        const int s = b - 14400;
        const float4* xr4 = (const float4*)(x + (size_t)s * HID);   // 720 float4s
        float ss = 0.f;
        for (int i = tid; i < 720; i += 256) {
            float4 v = xr4[i];
            ss += v.x * v.x + v.y * v.y + v.z * v.z + v.w * v.w;
        }
        for (int off = 32; off > 0; off >>= 1) ss += __shfl_down(ss, off);
        if ((tid & 63) == 0) red[tid >> 6] = ss;
        __syncthreads();
        float tot = red[0] + red[1] + red[2] + red[3];
        float scale = rsqrtf(tot / (float)HID + EPSV);
        const float4* ns4 = (const float4*)ns;
        u16x4* tr4 = (u16x4*)(t + (size_t)s * HID);
        for (int i = tid; i < 720; i += 256) {
            float4 v = xr4[i];
            float4 nv = ns4[i];
            u16x4 o;
            o.x = f2b(v.x * scale * nv.x);
            o.y = f2b(v.y * scale * nv.y);
            o.z = f2b(v.z * scale * nv.z);
            o.w = f2b(v.w * scale * nv.w);
            tr4[i] = o;
        }
    } else if (b < 16128) {                // YaRN rope tables (fp64 to match ref)
        int idx = (b - 15936) * 256 + tid;
        if (idx >= S_LEN * 32) return;
        int s = idx >> 5, i = idx & 31;
        const double PI2 = 6.283185307179586476925286766559;
        double base = 150000.0;
        double freq = pow(base, (double)(2 * i) / 64.0);
        double conc = 0.1 * log(32.0) + 1.0;
        double low  = 32.0 * log(4096.0 / (32.0 * PI2)) / log(base);
        double high = 32.0 * log(4096.0 / (1.0  * PI2)) / log(base);
        double interp = 1.0 / (32.0 * freq);
        double extrap = 1.0 / freq;
        double ramp = ((double)i - low) / (high - low);
        double msk = 1.0 - fmin(fmax(ramp, 0.0), 1.0);
        double invf = interp * (1.0 - msk) + extrap * msk;
        double ang = (double)s * invf;
        cosT[idx] = (float)(cos(ang) * conc);
        sinT[idx] = (float)(sin(ang) * conc);
    } else {                               // conv out_w (fused path only)
        int i = (b - 16128) * 256 + tid;
        float4 v = ((const float4*)out_w)[i];
        u16x4 o;
        o.x = f2b(v.x); o.y = f2b(v.y); o.z = f2b(v.z); o.w = f2b(v.w);
        ((u16x4*)out_w_bf)[i] = o;
    }
}

// ---------------- 0b. fp32 -> bf16 convert (out_w fallback path) ----------------
__global__ __launch_bounds__(256) void conv_bf16_kernel(
    const float* __restrict__ src, u16* __restrict__ dst, int n4)
{
    int i = blockIdx.x * 256 + threadIdx.x;
    if (i >= n4) return;
    float4 v = ((const float4*)src)[i];
    u16x4 o;
    o.x = f2b(v.x); o.y = f2b(v.y); o.z = f2b(v.z); o.w = f2b(v.w);
    ((u16x4*)dst)[i] = o;
}

// ---------------- 3. split-K GEMM, 256x256 tile, BK=64, 4-phase (r2 core) ----------------
// Cp[z][M,N](bf16) = A[M,K](bf16) * B[N,K]^T(bf16), K-chunk per z.
// GEMM-variant ledger: r2-BK64-2barrier = 52.0us VERIFIED x8 | r3-hoist = 54 |
// r9-256x128+2blk = 57.4 | r7-BK32-1barrier = ~50 but WAR-RACY |
// r17-fp32B-convert-on-stage = 75 (reg-load waits on barrier critical path).
// Race-freedom proof: staging writes to buf c^1 are separated from the
// previous tile's last reads of the same region by an intervening barrier
// (kh0-writes vs kh0-reads: barrier#2(t-1); kh1-writes vs kh1-reads:
// barrier#1(t)); reads are lgkm-consumed before each wave's next barrier.
// Counted vmcnt(6) at phases 0/2 keeps 3 half-tiles in flight (T3+T4);
// s_setprio around each 16-MFMA cluster (T5); never vmcnt(0) in main loop.
// z: 0,1 -> Cp + z*M*N (contiguous); 2 -> Cp2; 3 -> Cp3.
__global__ __launch_bounds__(512, 2) void gemm_bt_8p_kernel(
    const u16* __restrict__ A, const u16* __restrict__ B,
    u16* __restrict__ Cp, u16* __restrict__ Cp2, u16* __restrict__ Cp3,
    int M, int N, int K, int it0, int it1, int ntm, int ntn)
{
    extern __shared__ __align__(16) u16 smem[];
    u16* sAp = smem;            // [2][2][256*32] = 32768 elems
    u16* sBp = smem + 32768;

    const int tid  = threadIdx.x;
    const int wave = tid >> 6, lane = tid & 63;
    const int quad = lane >> 4, l16 = lane & 15;
    const int wm = wave >> 2, wn = wave & 3;

    // XCD-aware swizzle, general bijective form (m204) -- works for any grid
    const int nwg  = gridDim.x;
    const int q8   = nwg >> 3, r8 = nwg & 7;
    const int flat = blockIdx.x;
    const int xcd  = flat & 7, loc = flat >> 3;
    const int swz  = (xcd < r8) ? xcd * (q8 + 1) + loc
                                : r8 * (q8 + 1) + (xcd - r8) * q8 + loc;
    const int tpz  = ntm * ntn;
    const int z    = swz / tpz;
    const int rem  = swz - z * tpz;
    const int nt   = rem / ntm;
    const int mt   = rem - nt * ntm;
    const int bm = mt * 256, bn = nt * 256;
    const int niter = z ? it1 : it0;
    const int kb    = z ? (it0 + (z - 1) * it1) * 64 : 0;
    u16* C = (z == 0) ? Cp : (z == 1) ? (Cp + (size_t)M * N) : (z == 2) ? Cp2 : Cp3;

    // staging addresses: thread covers row (tid>>2) [+128], k-elems (tid&3)*8
    const int r2  = tid >> 2;
    const int ks8 = (tid & 3) * 8;
    const u16* gA0 = A + (size_t)(bm + r2) * K + kb + ks8;
    const u16* gA1 = gA0 + (size_t)128 * K;
    int brA = bn + r2;       if (brA > N - 1) brA = N - 1;   // N-pad clamp
    int brB = bn + 128 + r2; if (brB > N - 1) brB = N - 1;
    const u16* gB0 = B + (size_t)brA * K + kb + ks8;
    const u16* gB1 = B + (size_t)brB * K + kb + ks8;
    const int sw = wave * 512;          // wave-uniform LDS stage base (elems)

    f32x4 acc[8][4];
    #pragma unroll
    for (int i = 0; i < 8; i++)
        #pragma unroll
        for (int j = 0; j < 4; j++) acc[i][j] = (f32x4){0.f, 0.f, 0.f, 0.f};

    auto stA = [&](int c, int kh, int t) {
        u16* d = sAp + (((c << 1) | kh) << 13);
        const int koff = t * 64 + kh * 32;
        gld16(gA0 + koff, d + sw);
        gld16(gA1 + koff, d + 4096 + sw);
    };
    auto stB = [&](int c, int kh, int t) {
        u16* d = sBp + (((c << 1) | kh) << 13);
        const int koff = t * 64 + kh * 32;
        gld16(gB0 + koff, d + sw);
        gld16(gB1 + koff, d + 4096 + sw);
    };

    bf16x8 bv[4];
    const int arow = wm * 128 + l16;
    const int brow = wn * 64 + l16;
    auto rdB = [&](int c, int ks) {
        const u16* p = sBp + (((c << 1) | ks) << 13) + brow * 32 + quad * 8;
        #pragma unroll
        for (int nf = 0; nf < 4; nf++) bv[nf] = *(const bf16x8*)(p + nf * 16 * 32);
    };
    auto mmph = [&](int c, int ks, int mh) {
        const u16* p = sAp + (((c << 1) | ks) << 13) + (arow + mh * 64) * 32 + quad * 8;
        bf16x8 av[4];
        #pragma unroll
        for (int mf = 0; mf < 4; mf++) av[mf] = *(const bf16x8*)(p + mf * 16 * 32);
        __builtin_amdgcn_s_setprio(1);
        #pragma unroll
        for (int mf = 0; mf < 4; mf++)
            #pragma unroll
            for (int nf = 0; nf < 4; nf++)
                acc[mh * 4 + mf][nf] = __builtin_amdgcn_mfma_f32_16x16x32_bf16(
                    av[mf], bv[nf], acc[mh * 4 + mf][nf], 0, 0, 0);
        __builtin_amdgcn_s_setprio(0);
    };

    // prologue: stage tile 0 -> buf 0 (stream order Ak0,Bk0,Ak1,Bk1)
    stA(0, 0, 0); stB(0, 0, 0); stA(0, 1, 0); stB(0, 1, 0);

    for (int t = 0; t < niter - 1; ++t) {
        const int c = t & 1;
        // phase 0 (k0, mh0)
        stA(c ^ 1, 0, t + 1);
        WAIT_VM6();                       // tile t Ak0,Bk0 landed; 3 halves in flight
        __builtin_amdgcn_s_barrier();
        rdB(c, 0); mmph(c, 0, 0);
        // phase 1 (k0, mh1)
        stB(c ^ 1, 0, t + 1);
        mmph(c, 0, 1);
        // phase 2 (k1, mh0)
        stA(c ^ 1, 1, t + 1);
        WAIT_VM6();                       // tile t Ak1,Bk1 landed
        __builtin_amdgcn_s_barrier();
        rdB(c, 1); mmph(c, 1, 0);
        // phase 3 (k1, mh1)
        stB(c ^ 1, 1, t + 1);
        mmph(c, 1, 1);
    }
    {   // last tile: nothing staged, so counts differ (drain 4 -> 0)
        const int c = (niter - 1) & 1;
        WAIT_VM4();
        __builtin_amdgcn_s_barrier();
        rdB(c, 0); mmph(c, 0, 0); mmph(c, 0, 1);
        WAIT_VM0();
        __builtin_amdgcn_s_barrier();
        rdB(c, 1); mmph(c, 1, 0); mmph(c, 1, 1);
    }

    #pragma unroll
    for (int im = 0; im < 8; im++) {
        const int row0 = bm + wm * 128 + im * 16 + quad * 4;
        #pragma unroll
        for (int nf = 0; nf < 4; nf++) {
            const int col = bn + wn * 64 + nf * 16 + l16;
            if (col < N) {
                #pragma unroll
                for (int r = 0; r < 4; r++)
                    C[(size_t)(row0 + r) * N + col] = f2b(acc[im][nf][r]);
            }
        }
    }
}

// ---------------- 4. RoPE apply (VECTORIZED) + split-K reduce + bias + FUSED V-transpose ----------------
// Grid sections: [0,1728) rope heads (idx over S_LEN*288 chunks: 64 Q + 8 K
// heads, 4 chunks each); [1728,1920) V-transpose blocks that read qkvp0/1 +
// bias directly (recompute the V add -- 3 MB, free) and write vt transposed.
// Q is pre-scaled by SMSCALE*LOG2E: attention softmax uses native exp2.
__global__ __launch_bounds__(256) void rope_apply_kernel(
    const u16* __restrict__ p0, const u16* __restrict__ p1, const float* __restrict__ bias,
    const float* __restrict__ cosT, const float* __restrict__ sinT,
    u16* __restrict__ q_r, u16* __restrict__ k_r, u16* __restrict__ vt)
{
    __shared__ u16 tile[64][72];
    const int b = blockIdx.x;
    const int tid = threadIdx.x;
    if (b < 1728) {                      // rope heads: 64 Q + 8 K
        int idx = b * 256 + tid;         // s*288 + c, c in [0,288)
        int s = idx / 288;
        int c = idx - s * 288;
        const u16* r0p = p0 + (size_t)s * QKV_N;
        const u16* r1p = p1 + (size_t)s * QKV_N;
        int hh = c >> 2, j0 = (c & 3) * 8;
        int off = hh * 64;               // K heads land at QDIM+kh*64 = hh*64
        u16x8 a1 = *(const u16x8*)(r0p + off + j0);
        u16x8 b1 = *(const u16x8*)(r1p + off + j0);
        u16x8 a2 = *(const u16x8*)(r0p + off + 32 + j0);
        u16x8 b2 = *(const u16x8*)(r1p + off + 32 + j0);
        float bl[8], bh[8], cc[8], sn[8];
        *(float4*)&bl[0] = *(const float4*)(bias + off + j0);
        *(float4*)&bl[4] = *(const float4*)(bias + off + j0 + 4);
        *(float4*)&bh[0] = *(const float4*)(bias + off + 32 + j0);
        *(float4*)&bh[4] = *(const float4*)(bias + off + 32 + j0 + 4);
        *(float4*)&cc[0] = *(const float4*)(cosT + s * 32 + j0);
        *(float4*)&cc[4] = *(const float4*)(cosT + s * 32 + j0 + 4);
        *(float4*)&sn[0] = *(const float4*)(sinT + s * 32 + j0);
        *(float4*)&sn[4] = *(const float4*)(sinT + s * 32 + j0 + 4);
        const float scale = (hh < 64) ? SMSCALE * LOG2E : 1.0f;
        u16x8 lo, hi;
        #pragma unroll
        for (int j = 0; j < 8; j++) {
            float x1 = b2f(a1[j]) + b2f(b1[j]) + bl[j];
            float x2 = b2f(a2[j]) + b2f(b2[j]) + bh[j];
            lo[j] = f2b((x1 * cc[j] - x2 * sn[j]) * scale);
            hi[j] = f2b((x2 * cc[j] + x1 * sn[j]) * scale);
        }
        if (hh < 64) {
            u16* dst = q_r + (size_t)s * QDIM + off;
            *(u16x8*)(dst + j0) = lo;
            *(u16x8*)(dst + 32 + j0) = hi;
        } else {
            u16* dst = k_r + (size_t)s * KVDIM + (hh - 64) * 64;
            *(u16x8*)(dst + j0) = lo;
            *(u16x8*)(dst + 32 + j0) = hi;
        }
    } else {                             // V-transpose: vb in [0,192) = kvh*24 + sblk
        int vb = b - 1728;
        int kvh = vb / 24, sblk = vb - kvh * 24;
        int s0 = sblk * 64;
        int r = tid >> 3;                // 0..31
        int cc = (tid & 7) * 8;          // 0..56
        int off = QDIM + KVDIM + kvh * 64 + cc;
        float bb[8];
        *(float4*)&bb[0] = *(const float4*)(bias + off);
        *(float4*)&bb[4] = *(const float4*)(bias + off + 4);
        #pragma unroll
        for (int rr = 0; rr < 64; rr += 32) {
            int s = s0 + r + rr;
            u16x8 a = *(const u16x8*)(p0 + (size_t)s * QKV_N + off);
            u16x8 b2 = *(const u16x8*)(p1 + (size_t)s * QKV_N + off);
            #pragma unroll
            for (int j = 0; j < 8; j++)
                tile[cc + j][r + rr] = f2b(b2f(a[j]) + b2f(b2[j]) + bb[j]);
        }
        __syncthreads();
        #pragma unroll
        for (int rr = 0; rr < 64; rr += 32) {
            uint4 ov;
            u16* p = (u16*)&ov;
            #pragma unroll
            for (int j = 0; j < 8; j++) p[j] = tile[r + rr][cc + j];
            *(uint4*)(vt + (size_t)(kvh * 64 + r + rr) * S_LEN + s0 + cc) = ov;
        }
    }
}

// ---------------- 5. Flash attention, TRANSPOSED-SCORE form, native-exp2 softmax ----------------
// (round-2 structure + r12 exp2n + r14 ones-MFMA denominator & max3-tree.)
// Denominator via ONES-MFMA: lsum = mfma(ones, P) makes every output row =
// sum_k P[k][q]; deletes 15 serial adds + 2 shfls from the VALU chain.
// Scores arrive pre-scaled by log2e (folded into Q). Defer-max THR=11 log2.
__global__ __launch_bounds__(256) void attn_kernel(
    const u16* __restrict__ q_r, const u16* __restrict__ k_r, const u16* __restrict__ vt,
    const float* __restrict__ sinks, u16* __restrict__ o)
{
    __shared__ __align__(16) u16 sK[2][64 * 72];   // keys x d, pad 72, double-buffered
    __shared__ __align__(16) u16 sVt[2][64 * 72];  // d x keys, pad 72, double-buffered
    __shared__ __align__(16) u16 sP[4 * 16 * 72];  // per-wave: 16 queries x 64 keys

    const int bx = blockIdx.x, h = blockIdx.y;
    const int kvh = h & 7;
    const int tid = threadIdx.x, wave = tid >> 6, lane = tid & 63;
    const int quad = lane >> 4, l16 = lane & 15;
    const int srow = tid >> 3;            // 0..31
    const int scol = (tid & 7) * 8;       // 0..56
    u16* sPw = sP + wave * 16 * 72;
    const float sinkv = sinks[h] * LOG2E;   // log2-domain

    bf16x8 vone;                          // bf16 1.0 in every slot (ones-MFMA A-frag)
    #pragma unroll
    for (int j = 0; j < 8; j++) vone[j] = (short)0x3F80;

    // async-stage registers (tile t+1 in flight while computing tile t)
    uint4 kreg0, kreg1, vreg0, vreg1;
    const u16* kbase = k_r + (size_t)srow * KVDIM + kvh * 64 + scol;
    const u16* vbase = vt + (size_t)(kvh * 64 + srow) * S_LEN + scol;

    auto issue = [&](int j0) {
        kreg0 = *(const uint4*)(kbase + (size_t)j0 * KVDIM);
        kreg1 = *(const uint4*)(kbase + (size_t)(j0 + 32) * KVDIM);
        vreg0 = *(const uint4*)(vbase + j0);
        vreg1 = *(const uint4*)(vbase + (size_t)32 * S_LEN + j0);
    };
    auto lwrite = [&](int c) {
        *(uint4*)(&sK[c][srow * 72 + scol])        = kreg0;
        *(uint4*)(&sK[c][(srow + 32) * 72 + scol]) = kreg1;
        *(uint4*)(&sVt[c][srow * 72 + scol])        = vreg0;
        *(uint4*)(&sVt[c][(srow + 32) * 72 + scol]) = vreg1;
    };

    for (int phase = 0; phase < 2; ++phase) {
        const int qt = phase ? (23 - bx) : bx;
        const int q_i = qt * 64 + wave * 16 + l16;      // this lane's query row
        const u16* qp = q_r + (size_t)q_i * QDIM + h * 64 + quad * 8;
        bf16x8 aq0 = *(const bf16x8*)(qp);
        bf16x8 aq1 = *(const bf16x8*)(qp + 32);

        float m_i = sinkv, l_i = 1.0f;
        f32x4 acc[4];
        #pragma unroll
        for (int dt = 0; dt < 4; dt++) acc[dt] = (f32x4){0.f, 0.f, 0.f, 0.f};

        const int ntile = qt + 1;
        issue(0);
        __syncthreads();     // phase boundary: all waves done reading prev phase's LDS

        for (int tt = 0; tt < ntile; ++tt) {
            const int c = tt & 1;
            lwrite(c);                           // reg->LDS (implicit vmcnt wait, hidden)
            if (tt + 1 < ntile) issue((tt + 1) * 64);   // prefetch next tile
            WAIT_LGKM0();                        // my ds_writes visible
            __builtin_amdgcn_s_barrier();        // everyone's tile tt staged; buf c^1 free

            // S^T: 64 keys (m, 4 tiles) x 16 queries (n) per wave
            f32x4 sc[4];
            __builtin_amdgcn_s_setprio(1);
            #pragma unroll
            for (int nt = 0; nt < 4; nt++) {
                const u16* kp = &sK[c][(nt * 16 + l16) * 72 + quad * 8];
                bf16x8 bk0 = *(const bf16x8*)(kp);
                bf16x8 bk1 = *(const bf16x8*)(kp + 32);
                f32x4 s0 = (f32x4){0.f, 0.f, 0.f, 0.f};
                s0 = __builtin_amdgcn_mfma_f32_16x16x32_bf16(bk0, aq0, s0, 0, 0, 0);  // swapped!
                s0 = __builtin_amdgcn_mfma_f32_16x16x32_bf16(bk1, aq1, s0, 0, 0, 0);
                sc[nt] = s0;
            }
            __builtin_amdgcn_s_setprio(0);

            // causal mask: only the diagonal chunk (block-uniform branch)
            if (tt == qt) {
                #pragma unroll
                for (int nt = 0; nt < 4; nt++)
                    #pragma unroll
                    for (int r = 0; r < 4; r++)
                        if (tt * 64 + nt * 16 + quad * 4 + r > q_i) sc[nt][r] = -INFINITY;
            }

            // per-lane online softmax (log2 domain, native exp2), defer-max THR=11
            // max as max3-fusable tree (depth ~4 vs 15-deep serial chain)
            float a0 = fmaxf(fmaxf(sc[0][0], sc[0][1]), sc[0][2]);
            float a1 = fmaxf(fmaxf(sc[0][3], sc[1][0]), sc[1][1]);
            float a2 = fmaxf(fmaxf(sc[1][2], sc[1][3]), sc[2][0]);
            float a3 = fmaxf(fmaxf(sc[2][1], sc[2][2]), sc[2][3]);
            float a4 = fmaxf(fmaxf(sc[3][0], sc[3][1]), sc[3][2]);
            float vmax = fmaxf(fmaxf(fmaxf(a0, a1), fmaxf(a2, a3)),
                               fmaxf(a4, sc[3][3]));
            vmax = fmaxf(vmax, __shfl_xor(vmax, 16));
            vmax = fmaxf(vmax, __shfl_xor(vmax, 32));
            if (__any(vmax > m_i + 11.0f)) {     // rescale only when max grew enough
                float mnew = fmaxf(m_i, vmax);
                float alpha = exp2n(m_i - mnew);
                l_i *= alpha;
                #pragma unroll
                for (int dt = 0; dt < 4; dt++)
                    #pragma unroll
                    for (int r = 0; r < 4; r++) acc[dt][r] *= alpha;
                m_i = mnew;
            }
            u16x4 pk[4];
            #pragma unroll
            for (int nt = 0; nt < 4; nt++) {
                #pragma unroll
                for (int r = 0; r < 4; r++)
                    pk[nt][r] = f2b(exp2n(sc[nt][r] - m_i));   // bounded by 2^11
            }
            // P[q][key]: 4 contiguous keys per (nt,quad) -> packed 8B stores
            #pragma unroll
            for (int nt = 0; nt < 4; nt++)
                *(u16x4*)(sPw + l16 * 72 + nt * 16 + quad * 4) = pk[nt];
            __threadfence_block();   // order sP writes before cross-lane reads (wave-internal)

            // O^T += V^T (64xd as A) * P (16q x 64k as B); denominator via
            // ones-MFMA: every row of mfma(ones, P) = sum_k P[k][q].
            bf16x8 ap0 = *(const bf16x8*)(sPw + l16 * 72 + quad * 8);
            bf16x8 ap1 = *(const bf16x8*)(sPw + l16 * 72 + 32 + quad * 8);
            __builtin_amdgcn_s_setprio(1);
            f32x4 lsum = (f32x4){0.f, 0.f, 0.f, 0.f};
            lsum = __builtin_amdgcn_mfma_f32_16x16x32_bf16(vone, ap0, lsum, 0, 0, 0);
            lsum = __builtin_amdgcn_mfma_f32_16x16x32_bf16(vone, ap1, lsum, 0, 0, 0);
            #pragma unroll
            for (int dt = 0; dt < 4; dt++) {
                const u16* vp = &sVt[c][(dt * 16 + l16) * 72 + quad * 8];
                bf16x8 bv0 = *(const bf16x8*)(vp);
                bf16x8 bv1 = *(const bf16x8*)(vp + 32);
                acc[dt] = __builtin_amdgcn_mfma_f32_16x16x32_bf16(bv0, ap0, acc[dt], 0, 0, 0);  // swapped!
                acc[dt] = __builtin_amdgcn_mfma_f32_16x16x32_bf16(bv1, ap1, acc[dt], 0, 0, 0);
            }
            __builtin_amdgcn_s_setprio(0);
            l_i += lsum[0];                      // this lane's query denominator
        }

        // O^T: col=query(l16) = this lane's q_i; row = d = dt*16 + quad*4 + r
        float inv = 1.0f / l_i;
        #pragma unroll
        for (int dt = 0; dt < 4; dt++) {
            u16x4 ov;
            #pragma unroll
            for (int r = 0; r < 4; r++) ov[r] = f2b(acc[dt][r] * inv);
            *(u16x4*)(o + (size_t)q_i * QDIM + h * 64 + dt * 16 + quad * 4) = ov;
        }
    }
}

// ---------------- 6. final: out = p0 + p1 + p2 [+ p3] + out_b + x (8 elems/thread) ----------------
__global__ __launch_bounds__(256) void final_add_kernel(
    const u16* __restrict__ p0, const u16* __restrict__ p1, const u16* __restrict__ p2,
    const u16* __restrict__ p3, int np,
    const float* __restrict__ bias, const float* __restrict__ x, float* __restrict__ out)
{
    int i = blockIdx.x * 256 + threadIdx.x;        // group of 8 elems (8 | HID)
    int base = i * 8;
    int col = base % HID;
    float4 xo0 = *(const float4*)(x + base);
    float4 xo1 = *(const float4*)(x + base + 4);
    float4 bi0 = *(const float4*)(bias + col);
    float4 bi1 = *(const float4*)(bias + col + 4);
    u16x8 a = ((const u16x8*)p0)[i];
    u16x8 b = ((const u16x8*)p1)[i];
    u16x8 c = ((const u16x8*)p2)[i];
    float s[8];
    #pragma unroll
    for (int j = 0; j < 8; j++) s[j] = b2f(a[j]) + b2f(b[j]) + b2f(c[j]);
    if (np == 4) {                                  // uniform branch
        u16x8 d = ((const u16x8*)p3)[i];
        #pragma unroll
        for (int j = 0; j < 8; j++) s[j] += b2f(d[j]);
    }
    float4 r0, r1;
    r0.x = s[0] + bi0.x + xo0.x;
    r0.y = s[1] + bi0.y + xo0.y;
    r0.z = s[2] + bi0.z + xo0.z;
    r0.w = s[3] + bi0.w + xo0.w;
    r1.x = s[4] + bi1.x + xo1.x;
    r1.y = s[5] + bi1.y + xo1.y;
    r1.z = s[6] + bi1.z + xo1.z;
    r1.w = s[7] + bi1.w + xo1.w;
    *(float4*)(out + base) = r0;
    *(float4*)(out + base + 4) = r1;
}

// ---------------- launch ----------------
extern "C" void kernel_launch(void* const* d_in, const int* in_sizes, int n_in,
                              void* d_out, int out_size, void* d_ws, size_t ws_size,
                              hipStream_t stream)
{
    const float* x          = (const float*)d_in[0];
    const float* sinks      = (const float*)d_in[1];
    const float* norm_scale = (const float*)d_in[2];
    const float* qkv_w      = (const float*)d_in[3];
    const float* qkv_b      = (const float*)d_in[4];
    const float* out_w      = (const float*)d_in[5];
    const float* out_b      = (const float*)d_in[6];
    float* out = (float*)d_out;

    char* ws = (char*)d_ws;
    // Phase A: t @0, qkv_w_bf @8.85M, qkvp0 @38.34M, qkvp1 @54.07M (= qkvp0 + M*N, CONTIGUOUS)
    u16* t        = (u16*)(ws);                  // 8,847,360
    u16* qkv_w_bf = (u16*)(ws + 8847360);        // 29,491,200 -> 38,338,560
    u16* qkvp0    = (u16*)(ws + 38338560);       // 15,728,640 -> 54,067,200
    u16* qkvp1    = (u16*)(ws + 54067200);       // 15,728,640 -> 69,795,840  (qkvp0 + 1536*5120*2 OK)
    float* cosT   = (float*)(ws + 69795840);     // 196,608
    float* sinT   = (float*)(ws + 69992448);     // 196,608 (total 70,189,056)
    // Phase B: k_r @0, vt @1.57M, q_r @3.15M, o @15.73M,
    //   outp0 @28.31M, outp1 @37.16M (contiguous), outp2 @3.15M (overlays dead q_r),
    //   out_w_bf: fused -> fresh region @70.19M (needs ws >= 93.78M);
    //             fallback -> @46.01M (overlays dead qkvp0/1, conv after rope_apply).
    //   (v_r eliminated: rope_apply writes vt directly via fused transpose.)
    u16* k_r      = (u16*)(ws);                  // 1,572,864
    u16* vt       = (u16*)(ws + 1572864);        // 1,572,864 -> 3,145,728
    u16* q_r      = (u16*)(ws + 3145728);        // 12,582,912 -> 15,728,640
    u16* o        = (u16*)(ws + 15728640);       // 12,582,912 -> 28,311,552
    u16* outp0    = (u16*)(ws + 28311552);       // 8,847,360 -> 37,158,912
    u16* outp1    = (u16*)(ws + 37158912);       // 8,847,360 -> 46,006,272
    u16* outp2    = (u16*)(ws + 3145728);        // 8,847,360 -> 11,993,088 (inside dead q_r region)

    const bool fuse_outw = (ws_size >= 93782016ull);   // 70,189,056 + 23,592,960
    u16* out_w_bf = fuse_outw ? (u16*)(ws + 70189056) : (u16*)(ws + 46006272);

    static bool lds_attr_set = false;
    if (!lds_attr_set) {
        hipFuncSetAttribute(reinterpret_cast<const void*>(gemm_bt_8p_kernel),
                            hipFuncAttributeMaxDynamicSharedMemorySize, 131072);
        lds_attr_set = true;
    }

    // fused prep: conv(qkv_w) [14400] + rmsnorm [1536] + rope tables [192]
    //             (+ conv(out_w) [11520] when workspace allows)
    prep_kernel<<<fuse_outw ? 27648 : 16128, 256, 0, stream>>>(
        qkv_w, qkv_w_bf, x, norm_scale, t, cosT, sinT, out_w, out_w_bf);
    // QKV GEMM: M=1536 N=5120 K=2880. 256^2 tiles: 6x20=120, split-K 2
    // (23/22 K-steps of 64) -> 240 blocks.
    gemm_bt_8p_kernel<<<240, 512, 131072, stream>>>(
        t, qkv_w_bf, qkvp0, qkvp0, qkvp0, S_LEN, QKV_N, HID, 23, 22, 6, 20);
    // rope [1728 blocks] + fused V-transpose [192 blocks]
    rope_apply_kernel<<<1920, 256, 0, stream>>>(
        qkvp0, qkvp1, qkv_b, cosT, sinT, q_r, k_r, vt);
    if (!fuse_outw)
        conv_bf16_kernel<<<(HID * QDIM / 4 + 255) / 256, 256, 0, stream>>>(out_w, out_w_bf, HID * QDIM / 4);
    attn_kernel<<<dim3(12, NH), 256, 0, stream>>>(q_r, k_r, vt, sinks, o);
    // out GEMM: M=1536 N=2880 K=4096 (64 K-steps of 64). 256^2 tiles: 6x12
    // (N padded 2880->3072, B rows clamped, stores masked), split-K 3
    // (22/21/21) -> 216 blocks. z=0,1 -> outp0,outp1 (contiguous); z=2 -> outp2.
    gemm_bt_8p_kernel<<<216, 512, 131072, stream>>>(
        o, out_w_bf, outp0, outp2, outp2, S_LEN, HID, QDIM, 22, 21, 6, 12);
    final_add_kernel<<<S_LEN * HID / 8 / 256, 256, 0, stream>>>(
        outp0, outp1, outp2, outp2, 3, out_b, x, out);
}